// Round 4
// baseline (1102.561 us; speedup 1.0000x reference)
//
#include <hip/hip_runtime.h>
#include <hip/hip_bf16.h>
#include <math.h>

#define N1      20000          // nodes per graph
#define NT      40000          // both graphs
#define E1      640000         // edges per graph
#define ET      1280000
#define FIN_D   256
#define HID_D   512
#define TOPK    1000
#define MP      40064          // 313 * 128  (padded M for both graphs)
#define SCAN_NB 157            // ceil(40000/256)

typedef __attribute__((ext_vector_type(8))) short short8;
typedef __attribute__((ext_vector_type(4))) float floatx4;

__device__ __forceinline__ unsigned short f2bf(float f) {
    union { __hip_bfloat16 h; unsigned short u; } cv;
    cv.h = __float2bfloat16(f);
    return cv.u;
}
__device__ __forceinline__ float bflo(unsigned int u) {
    union { unsigned int i; float f; } c; c.i = u << 16; return c.f;
}
__device__ __forceinline__ float bfhi(unsigned int u) {
    union { unsigned int i; float f; } c; c.i = u & 0xffff0000u; return c.f;
}

// ---------------- CSR build (both graphs in one node space) ----------------
__global__ void hist_kernel(const int* __restrict__ ei1, const int* __restrict__ ei2,
                            int* __restrict__ deg) {
    int e = blockIdx.x * blockDim.x + threadIdx.x;
    if (e >= ET) return;
    int d = (e < E1) ? ei1[E1 + e] : (ei2[E1 + (e - E1)] + N1);
    atomicAdd(&deg[d], 1);
}

__global__ void scan1_kernel(const int* __restrict__ deg, int* __restrict__ tmp,
                             int* __restrict__ bsum) {
    __shared__ int tile[256];
    int t = threadIdx.x;
    int i = blockIdx.x * 256 + t;
    int v = (i < NT) ? deg[i] : 0;
    tile[t] = v;
    __syncthreads();
    for (int off = 1; off < 256; off <<= 1) {
        int x = (t >= off) ? tile[t - off] : 0;
        __syncthreads();
        tile[t] += x;
        __syncthreads();
    }
    if (i < NT) tmp[i] = tile[t] - v;
    if (t == 255) bsum[blockIdx.x] = tile[255];
}

__global__ void scan2_kernel(const int* __restrict__ bsum, int* __restrict__ boff,
                             int* __restrict__ row_start) {
    __shared__ int tile[256];
    int t = threadIdx.x;
    int v = (t < SCAN_NB) ? bsum[t] : 0;
    tile[t] = v;
    __syncthreads();
    for (int off = 1; off < 256; off <<= 1) {
        int x = (t >= off) ? tile[t - off] : 0;
        __syncthreads();
        tile[t] += x;
        __syncthreads();
    }
    if (t < SCAN_NB) boff[t] = tile[t] - v;
    if (t == 255) row_start[NT] = tile[255];
}

__global__ void scan3_kernel(const int* __restrict__ tmp, const int* __restrict__ boff,
                             int* __restrict__ row_start, int* __restrict__ cursor) {
    int i = blockIdx.x * 256 + threadIdx.x;
    if (i < NT) {
        int rs = tmp[i] + boff[blockIdx.x];
        row_start[i] = rs;
        cursor[i] = rs;
    }
}

__global__ void fill_kernel(const int* __restrict__ ei1, const int* __restrict__ ei2,
                            int* __restrict__ cursor, int* __restrict__ csr_src) {
    int e = blockIdx.x * blockDim.x + threadIdx.x;
    if (e >= ET) return;
    int s, d;
    if (e < E1) { s = ei1[e]; d = ei1[E1 + e]; }
    else        { int e2 = e - E1; s = ei2[e2] + N1; d = ei2[E1 + e2] + N1; }
    int p = atomicAdd(&cursor[d], 1);
    csr_src[p] = s;
}

// ---------------- conversions ----------------
__global__ void convx_kernel(const float* __restrict__ x, unsigned short* __restrict__ xb, int n4) {
    int i = blockIdx.x * 256 + threadIdx.x;
    if (i < n4) {
        float4 f = ((const float4*)x)[i];
        ushort4 u;
        u.x = f2bf(f.x); u.y = f2bf(f.y); u.z = f2bf(f.z); u.w = f2bf(f.w);
        ((ushort4*)xb)[i] = u;
    }
}

// W[K][N] fp32 -> Wt[N][K] bf16 (tiled transpose)
__global__ void convw_kernel(const float* __restrict__ W, unsigned short* __restrict__ Wt,
                             int K, int N) {
    __shared__ float tile[32][33];
    int k0 = blockIdx.x * 32, n0 = blockIdx.y * 32;
    int tx = threadIdx.x & 31, ty = threadIdx.x >> 5;
    for (int r = ty; r < 32; r += 8) tile[r][tx] = W[(size_t)(k0 + r) * N + n0 + tx];
    __syncthreads();
    for (int r = ty; r < 32; r += 8)
        Wt[(size_t)(n0 + r) * K + k0 + tx] = f2bf(tile[tx][r]);
}

// ---------------- GIN aggregation, XCD-slab version ----------------
// Feature dim split into NSLAB slabs of 32 cols (4 uint4). slab % 8 == blockIdx % 8
// keeps one slab per XCD (round-robin block->XCD) => per-XCD working set = NT*32cols*2B
// = 2.56 MB < 4 MB L2. For NSLAB=16 (D=512), two temporal phases via block ordering.
#define ACC8(u) do { \
    acc[0] += bflo((u).x); acc[1] += bfhi((u).x); \
    acc[2] += bflo((u).y); acc[3] += bfhi((u).y); \
    acc[4] += bflo((u).z); acc[5] += bfhi((u).z); \
    acc[6] += bflo((u).w); acc[7] += bfhi((u).w); } while (0)

template<int LPR, int NSLAB>   // LPR = uint4 per full row (D/8); NSLAB = LPR/4
__global__ void agg_slab_kernel(const unsigned short* __restrict__ x,
                                const int* __restrict__ row_start,
                                const int* __restrict__ csr_src,
                                unsigned short* __restrict__ h) {
    const int GRPS = NT / 64;                  // 625 node-groups of 64
    int b = blockIdx.x;
    int phase = b / (8 * GRPS);                // 0..NSLAB/8-1
    int rem = b % (8 * GRPS);
    int slab = phase * 8 + (rem & 7);          // stays on XCD (rem&7)
    int grp = rem >> 3;
    int nid = grp * 64 + (threadIdx.x >> 2);
    int c = threadIdx.x & 3;
    int chunk = slab * 4 + c;                  // uint4 index within row
    const uint4* X = (const uint4*)x;
    uint4 v = X[(size_t)nid * LPR + chunk];
    float acc[8];
    acc[0] = bflo(v.x); acc[1] = bfhi(v.x);
    acc[2] = bflo(v.y); acc[3] = bfhi(v.y);
    acc[4] = bflo(v.z); acc[5] = bfhi(v.z);
    acc[6] = bflo(v.w); acc[7] = bfhi(v.w);
    int s = row_start[nid], e = row_start[nid + 1];
    int p = s;
    for (; p + 4 <= e; p += 4) {
        int n0 = csr_src[p], n1 = csr_src[p + 1], n2 = csr_src[p + 2], n3 = csr_src[p + 3];
        uint4 u0 = X[(size_t)n0 * LPR + chunk];
        uint4 u1 = X[(size_t)n1 * LPR + chunk];
        uint4 u2 = X[(size_t)n2 * LPR + chunk];
        uint4 u3 = X[(size_t)n3 * LPR + chunk];
        ACC8(u0); ACC8(u1); ACC8(u2); ACC8(u3);
    }
    for (; p < e; ++p) {
        int sn = csr_src[p];
        uint4 u = X[(size_t)sn * LPR + chunk];
        ACC8(u);
    }
    uint4 o;
    o.x = (unsigned)f2bf(acc[0]) | ((unsigned)f2bf(acc[1]) << 16);
    o.y = (unsigned)f2bf(acc[2]) | ((unsigned)f2bf(acc[3]) << 16);
    o.z = (unsigned)f2bf(acc[4]) | ((unsigned)f2bf(acc[5]) << 16);
    o.w = (unsigned)f2bf(acc[6]) | ((unsigned)f2bf(acc[7]) << 16);
    ((uint4*)h)[(size_t)nid * LPR + chunk] = o;
}

// ---------------- bf16 MFMA GEMM: C = relu(A[MP,K] @ W[K,N] + bias), bf16 out ----
__launch_bounds__(256)
__global__ void gemm_mfma(const unsigned short* __restrict__ A,
                          const unsigned short* __restrict__ Wt,
                          const float* __restrict__ bias,
                          unsigned short* __restrict__ C,
                          int K, int N) {
    __shared__ unsigned short As[128 * 32];
    __shared__ unsigned short Bs[128 * 32];
    int tid = threadIdx.x;
    int lane = tid & 63;
    int w = tid >> 6;
    int wr = w >> 1, wc = w & 1;
    int row0 = blockIdx.x * 128;
    int col0 = blockIdx.y * 128;
    floatx4 acc[4][4] = {};
    int lr = tid >> 2;
    int c8 = (tid & 3) * 8;
    const unsigned short* Ag = A + (size_t)row0 * K;
    const unsigned short* Bg = Wt + (size_t)col0 * K;

    for (int kt = 0; kt < K; kt += 32) {
#pragma unroll
        for (int l = 0; l < 2; ++l) {
            int r = l * 64 + lr;
            __builtin_amdgcn_global_load_lds(
                (const __attribute__((address_space(1))) void*)(Ag + (size_t)r * K + kt + c8),
                (__attribute__((address_space(3))) void*)(As + l * 2048 + tid * 8),
                16, 0, 0);
            __builtin_amdgcn_global_load_lds(
                (const __attribute__((address_space(1))) void*)(Bg + (size_t)r * K + kt + c8),
                (__attribute__((address_space(3))) void*)(Bs + l * 2048 + tid * 8),
                16, 0, 0);
        }
        __syncthreads();
        short8 af[4], bf[4];
        int q8 = (lane >> 4) * 8;
#pragma unroll
        for (int i = 0; i < 4; ++i) {
            int m = wr * 64 + i * 16 + (lane & 15);
            af[i] = *(const short8*)&As[m * 32 + q8];
            int n = wc * 64 + i * 16 + (lane & 15);
            bf[i] = *(const short8*)&Bs[n * 32 + q8];
        }
#pragma unroll
        for (int i = 0; i < 4; ++i)
#pragma unroll
            for (int j = 0; j < 4; ++j)
                acc[i][j] = __builtin_amdgcn_mfma_f32_16x16x32_bf16(af[i], bf[j], acc[i][j], 0, 0, 0);
        __syncthreads();
    }
    int q = lane >> 4;
    int cn = lane & 15;
#pragma unroll
    for (int j = 0; j < 4; ++j) {
        int col = col0 + wc * 64 + j * 16 + cn;
        float bv = bias[col];
#pragma unroll
        for (int i = 0; i < 4; ++i) {
            int rowb = row0 + wr * 64 + i * 16 + q * 4;
#pragma unroll
            for (int r = 0; r < 4; ++r) {
                float vv = fmaxf(acc[i][j][r] + bv, 0.f);
                C[(size_t)(rowb + r) * N + col] = f2bf(vv);
            }
        }
    }
}

// ---------------- final linear [NT,512]bf16 @ [512,2]fp32 + b ----------------
__global__ void lin_kernel(const unsigned short* __restrict__ A, const float* __restrict__ w,
                           const float* __restrict__ b, float* __restrict__ o, int M) {
    int wave = threadIdx.x >> 6;
    int lane = threadIdx.x & 63;
    int row = blockIdx.x * 4 + wave;
    if (row >= M) return;
    const uint4* Ar = (const uint4*)(A + (size_t)row * 512);
    uint4 u = Ar[lane];
    float f[8];
    f[0] = bflo(u.x); f[1] = bfhi(u.x); f[2] = bflo(u.y); f[3] = bfhi(u.y);
    f[4] = bflo(u.z); f[5] = bfhi(u.z); f[6] = bflo(u.w); f[7] = bfhi(u.w);
    float s0 = 0.f, s1 = 0.f;
#pragma unroll
    for (int j = 0; j < 8; ++j) {
        int base = (lane * 8 + j) * 2;
        s0 = fmaf(f[j], w[base + 0], s0);
        s1 = fmaf(f[j], w[base + 1], s1);
    }
#pragma unroll
    for (int off = 32; off > 0; off >>= 1) {
        s0 += __shfl_down(s0, off, 64);
        s1 += __shfl_down(s1, off, 64);
    }
    if (lane == 0) { o[row * 2] = s0 + b[0]; o[row * 2 + 1] = s1 + b[1]; }
}

// ---------------- pairwise distance ----------------
__global__ void dist_kernel(const float* __restrict__ o, float* __restrict__ dist) {
    int i = blockIdx.x * blockDim.x + threadIdx.x;
    if (i < N1) {
        float2 a = ((const float2*)o)[i];
        float2 b = ((const float2*)o)[N1 + i];
        float d0 = a.x - b.x + 1e-6f, d1 = a.y - b.y + 1e-6f;
        dist[i] = sqrtf(d0 * d0 + d1 * d1);
    }
}

// ---------------- radix-select top-k ----------------
__global__ void histd_kernel(const float* __restrict__ dist, int* __restrict__ hist) {
    int i = blockIdx.x * blockDim.x + threadIdx.x;
    if (i < N1) {
        unsigned u = __float_as_uint(dist[i]);
        atomicAdd(&hist[u >> 19], 1);
    }
}

__global__ void selk_kernel(const int* __restrict__ hist, int* __restrict__ selout) {
    __shared__ int tile[256];
    int t = threadIdx.x;
    int running = 0;
    for (int tb = 0; tb < 16; ++tb) {
        int idx = 4095 - (tb * 256 + t);
        int v = hist[idx];
        tile[t] = v;
        __syncthreads();
        for (int off = 1; off < 256; off <<= 1) {
            int x = (t >= off) ? tile[t - off] : 0;
            __syncthreads();
            tile[t] += x;
            __syncthreads();
        }
        int incl = running + tile[t];
        if (incl >= TOPK && incl - v < TOPK) selout[0] = idx;
        running += tile[255];
        __syncthreads();
        if (running >= TOPK) break;
    }
}

__global__ void compact_kernel(const float* __restrict__ dist, const int* __restrict__ selout,
                               int* __restrict__ nc, float* __restrict__ cd, int* __restrict__ ci) {
    int i = blockIdx.x * blockDim.x + threadIdx.x;
    if (i >= N1) return;
    float d = dist[i];
    int b = (int)(__float_as_uint(d) >> 19);
    if (b >= selout[0]) {
        int p = atomicAdd(nc, 1);
        cd[p] = d;
        ci[p] = i;
    }
}

#define CCH 2048
__global__ void rankc_kernel(const float* __restrict__ cd, const int* __restrict__ ci,
                             const int* __restrict__ nc_p, float* __restrict__ vals) {
    __shared__ float ds[CCH];
    __shared__ int   di_[CCH];
    int nc = *nc_p;
    int t = threadIdx.x;
    int q = blockIdx.x * 256 + t;
    float dq = 0.f; int iq = 0;
    if (q < nc) { dq = cd[q]; iq = ci[q]; }
    int cnt = 0;
    for (int c0 = 0; c0 < nc; c0 += CCH) {
        int lim = min(CCH, nc - c0);
        for (int j = t; j < lim; j += 256) { ds[j] = cd[c0 + j]; di_[j] = ci[c0 + j]; }
        __syncthreads();
        if (q < nc) {
            for (int j = 0; j < lim; ++j) {
                float dj = ds[j];
                cnt += (dj > dq) || (dj == dq && di_[j] < iq);
            }
        }
        __syncthreads();
    }
    if (q < nc && cnt < TOPK) vals[cnt] = dq;
}

// ---------------- head MLP ----------------
__launch_bounds__(512)
__global__ void head_kernel(const float* __restrict__ vals,
                            const float* __restrict__ fc1_w, const float* __restrict__ fc1_b,
                            const float* __restrict__ ln1_g, const float* __restrict__ ln1_b,
                            const float* __restrict__ fc2_w, const float* __restrict__ fc2_b,
                            const float* __restrict__ ln2_g, const float* __restrict__ ln2_b,
                            const float* __restrict__ fc3_w, const float* __restrict__ fc3_b,
                            float* __restrict__ out) {
    __shared__ float sv[TOPK];
    __shared__ float a1[128];
    __shared__ float red[512];
    __shared__ float s_m, s_r;
    int t = threadIdx.x;
    for (int i = t; i < TOPK; i += 512) sv[i] = vals[i];
    __syncthreads();
    float h1 = 0.f;
    if (t < 128) {
        h1 = fc1_b[t];
        for (int j = 0; j < TOPK; ++j) h1 = fmaf(sv[j], fc1_w[j * 128 + t], h1);
    }
    red[t] = (t < 128) ? h1 : 0.f; __syncthreads();
    for (int s = 256; s > 0; s >>= 1) { if (t < s) red[t] += red[t + s]; __syncthreads(); }
    if (t == 0) s_m = red[0] / 128.f;
    __syncthreads();
    float m1 = s_m;
    float dv = (t < 128) ? (h1 - m1) : 0.f;
    red[t] = dv * dv; __syncthreads();
    for (int s = 256; s > 0; s >>= 1) { if (t < s) red[t] += red[t + s]; __syncthreads(); }
    if (t == 0) s_r = rsqrtf(red[0] / 128.f + 1e-5f);
    __syncthreads();
    float r1 = s_r;
    if (t < 128) a1[t] = fmaxf((h1 - m1) * r1 * ln1_g[t] + ln1_b[t], 0.f);
    __syncthreads();
    float h2 = fc2_b[t];
    for (int j = 0; j < 128; ++j) h2 = fmaf(a1[j], fc2_w[j * 512 + t], h2);
    red[t] = h2; __syncthreads();
    for (int s = 256; s > 0; s >>= 1) { if (t < s) red[t] += red[t + s]; __syncthreads(); }
    if (t == 0) s_m = red[0] / 512.f;
    __syncthreads();
    float m2 = s_m;
    float d2 = h2 - m2;
    red[t] = d2 * d2; __syncthreads();
    for (int s = 256; s > 0; s >>= 1) { if (t < s) red[t] += red[t + s]; __syncthreads(); }
    if (t == 0) s_r = rsqrtf(red[0] / 512.f + 1e-5f);
    __syncthreads();
    float r2 = s_r;
    float y2 = fmaxf((h2 - m2) * r2 * ln2_g[t] + ln2_b[t], 0.f);
    red[t] = y2 * fc3_w[t]; __syncthreads();
    for (int s = 256; s > 0; s >>= 1) { if (t < s) red[t] += red[t + s]; __syncthreads(); }
    if (t == 0) out[0] = 1.f / (1.f + expf(-(red[0] + fc3_b[0])));
}

extern "C" void kernel_launch(void* const* d_in, const int* in_sizes, int n_in,
                              void* d_out, int out_size, void* d_ws, size_t ws_size,
                              hipStream_t stream) {
    const float* x1   = (const float*)d_in[0];
    const int*   ei1  = (const int*)d_in[1];
    const float* x2   = (const float*)d_in[2];
    const int*   ei2  = (const int*)d_in[3];
    const float* w11  = (const float*)d_in[4];
    const float* b11  = (const float*)d_in[5];
    const float* w12  = (const float*)d_in[6];
    const float* b12  = (const float*)d_in[7];
    const float* w21  = (const float*)d_in[8];
    const float* b21  = (const float*)d_in[9];
    const float* w22  = (const float*)d_in[10];
    const float* b22  = (const float*)d_in[11];
    const float* w31  = (const float*)d_in[12];
    const float* b31  = (const float*)d_in[13];
    const float* w32  = (const float*)d_in[14];
    const float* b32  = (const float*)d_in[15];
    const float* lw   = (const float*)d_in[16];
    const float* lb   = (const float*)d_in[17];
    const float* fc1w = (const float*)d_in[18];
    const float* fc1b = (const float*)d_in[19];
    const float* ln1g = (const float*)d_in[20];
    const float* ln1b = (const float*)d_in[21];
    const float* fc2w = (const float*)d_in[22];
    const float* fc2b = (const float*)d_in[23];
    const float* ln2g = (const float*)d_in[24];
    const float* ln2b = (const float*)d_in[25];
    const float* fc3w = (const float*)d_in[26];
    const float* fc3b = (const float*)d_in[27];

    char* ws = (char*)d_ws;
    size_t off = 0;
    auto alloc = [&](size_t bytes) -> void* {
        void* p = ws + off;
        off += (bytes + 255) & ~(size_t)255;
        return p;
    };
    unsigned short* H0  = (unsigned short*)alloc((size_t)MP * HID_D * 2);
    unsigned short* H1  = (unsigned short*)alloc((size_t)MP * HID_D * 2);
    unsigned short* XB  = H1;   // alias: XB dead before gemm1 writes H1
    unsigned short* wt11 = (unsigned short*)alloc((size_t)HID_D * FIN_D * 2);
    unsigned short* wt12 = (unsigned short*)alloc((size_t)HID_D * HID_D * 2);
    unsigned short* wt21 = (unsigned short*)alloc((size_t)HID_D * HID_D * 2);
    unsigned short* wt22 = (unsigned short*)alloc((size_t)HID_D * HID_D * 2);
    unsigned short* wt31 = (unsigned short*)alloc((size_t)HID_D * HID_D * 2);
    unsigned short* wt32 = (unsigned short*)alloc((size_t)HID_D * HID_D * 2);
    float* o         = (float*)alloc((size_t)NT * 2 * 4);
    float* dist      = (float*)alloc((size_t)N1 * 4);
    float* vals      = (float*)alloc((size_t)TOPK * 4);
    int*   row_start = (int*)alloc((size_t)(NT + 1) * 4);
    int*   cursor    = (int*)alloc((size_t)NT * 4);
    int*   deg       = (int*)alloc((size_t)NT * 4);
    int*   scan_tmp  = (int*)alloc((size_t)NT * 4);
    int*   bsum      = (int*)alloc((size_t)SCAN_NB * 4);
    int*   boff      = (int*)alloc((size_t)SCAN_NB * 4);
    int*   csr_src   = (int*)alloc((size_t)ET * 4);
    int*   selblk    = (int*)alloc((size_t)(4096 + 64) * 4);  // hist + nc
    int*   hist      = selblk;
    int*   nc        = selblk + 4096;
    int*   selout    = (int*)alloc(2 * 4);
    float* cd        = (float*)alloc((size_t)N1 * 4);
    int*   ci        = (int*)alloc((size_t)N1 * 4);

    // ---- weight / input conversions ----
    {
        dim3 g11(FIN_D / 32, HID_D / 32);
        dim3 g55(HID_D / 32, HID_D / 32);
        convw_kernel<<<g11, 256, 0, stream>>>(w11, wt11, FIN_D, HID_D);
        convw_kernel<<<g55, 256, 0, stream>>>(w12, wt12, HID_D, HID_D);
        convw_kernel<<<g55, 256, 0, stream>>>(w21, wt21, HID_D, HID_D);
        convw_kernel<<<g55, 256, 0, stream>>>(w22, wt22, HID_D, HID_D);
        convw_kernel<<<g55, 256, 0, stream>>>(w31, wt31, HID_D, HID_D);
        convw_kernel<<<g55, 256, 0, stream>>>(w32, wt32, HID_D, HID_D);
        int n4 = N1 * FIN_D / 4;
        convx_kernel<<<(n4 + 255) / 256, 256, 0, stream>>>(x1, XB, n4);
        convx_kernel<<<(n4 + 255) / 256, 256, 0, stream>>>(x2, XB + (size_t)N1 * FIN_D, n4);
    }

    // ---- CSR build (both graphs, global node ids) ----
    hipMemsetAsync(deg, 0, NT * sizeof(int), stream);
    hist_kernel<<<(ET + 255) / 256, 256, 0, stream>>>(ei1, ei2, deg);
    scan1_kernel<<<SCAN_NB, 256, 0, stream>>>(deg, scan_tmp, bsum);
    scan2_kernel<<<1, 256, 0, stream>>>(bsum, boff, row_start);
    scan3_kernel<<<SCAN_NB, 256, 0, stream>>>(scan_tmp, boff, row_start, cursor);
    fill_kernel<<<(ET + 255) / 256, 256, 0, stream>>>(ei1, ei2, cursor, csr_src);

    // ---- GNN pipeline (both graphs batched) ----
    dim3 gemm_grid(MP / 128, HID_D / 128);
    const int GRPS = NT / 64;   // 625
    // layer 1 (D=256 input): 8 slabs
    agg_slab_kernel<32, 8><<<8 * GRPS, 256, 0, stream>>>(XB, row_start, csr_src, H0);
    gemm_mfma<<<gemm_grid, 256, 0, stream>>>(H0, wt11, b11, H1, FIN_D, HID_D);   // overwrites XB (dead)
    gemm_mfma<<<gemm_grid, 256, 0, stream>>>(H1, wt12, b12, H0, HID_D, HID_D);
    // layer 2 (D=512): 16 slabs, 2 phases
    agg_slab_kernel<64, 16><<<16 * GRPS, 256, 0, stream>>>(H0, row_start, csr_src, H1);
    gemm_mfma<<<gemm_grid, 256, 0, stream>>>(H1, wt21, b21, H0, HID_D, HID_D);
    gemm_mfma<<<gemm_grid, 256, 0, stream>>>(H0, wt22, b22, H1, HID_D, HID_D);
    // layer 3
    agg_slab_kernel<64, 16><<<16 * GRPS, 256, 0, stream>>>(H1, row_start, csr_src, H0);
    gemm_mfma<<<gemm_grid, 256, 0, stream>>>(H0, wt31, b31, H1, HID_D, HID_D);
    gemm_mfma<<<gemm_grid, 256, 0, stream>>>(H1, wt32, b32, H0, HID_D, HID_D);
    // final linear [NT,512] -> [NT,2]
    lin_kernel<<<(NT + 3) / 4, 256, 0, stream>>>(H0, lw, lb, o, NT);

    // ---- distance + radix-select top-k ----
    dist_kernel<<<(N1 + 255) / 256, 256, 0, stream>>>(o, dist);
    hipMemsetAsync(selblk, 0, (4096 + 64) * sizeof(int), stream);
    histd_kernel<<<(N1 + 255) / 256, 256, 0, stream>>>(dist, hist);
    selk_kernel<<<1, 256, 0, stream>>>(hist, selout);
    compact_kernel<<<(N1 + 255) / 256, 256, 0, stream>>>(dist, selout, nc, cd, ci);
    rankc_kernel<<<(N1 + 255) / 256, 256, 0, stream>>>(cd, ci, nc, vals);

    // ---- head MLP ----
    head_kernel<<<1, 512, 0, stream>>>(vals, fc1w, fc1b, ln1g, ln1b,
                                       fc2w, fc2b, ln2g, ln2b, fc3w, fc3b,
                                       (float*)d_out);
}

// Round 5
// 1051.157 us; speedup vs baseline: 1.0489x; 1.0489x over previous
//
#include <hip/hip_runtime.h>
#include <hip/hip_bf16.h>
#include <math.h>

#define N1      20000          // nodes per graph
#define NT      40000          // both graphs
#define E1      640000         // edges per graph
#define ET      1280000
#define FIN_D   256
#define HID_D   512
#define TOPK    1000
#define MP      40064          // 313 * 128  (padded M for both graphs)
#define SCAN_NB 157            // ceil(40000/256)

typedef __attribute__((ext_vector_type(8))) short short8;
typedef __attribute__((ext_vector_type(4))) float floatx4;

__device__ __forceinline__ unsigned short f2bf(float f) {
    union { __hip_bfloat16 h; unsigned short u; } cv;
    cv.h = __float2bfloat16(f);
    return cv.u;
}
__device__ __forceinline__ float bflo(unsigned int u) {
    union { unsigned int i; float f; } c; c.i = u << 16; return c.f;
}
__device__ __forceinline__ float bfhi(unsigned int u) {
    union { unsigned int i; float f; } c; c.i = u & 0xffff0000u; return c.f;
}

// ---------------- CSR build (both graphs in one node space) ----------------
__global__ void hist_kernel(const int* __restrict__ ei1, const int* __restrict__ ei2,
                            int* __restrict__ deg) {
    int e = blockIdx.x * blockDim.x + threadIdx.x;
    if (e >= ET) return;
    int d = (e < E1) ? ei1[E1 + e] : (ei2[E1 + (e - E1)] + N1);
    atomicAdd(&deg[d], 1);
}

__global__ void scan1_kernel(const int* __restrict__ deg, int* __restrict__ tmp,
                             int* __restrict__ bsum) {
    __shared__ int tile[256];
    int t = threadIdx.x;
    int i = blockIdx.x * 256 + t;
    int v = (i < NT) ? deg[i] : 0;
    tile[t] = v;
    __syncthreads();
    for (int off = 1; off < 256; off <<= 1) {
        int x = (t >= off) ? tile[t - off] : 0;
        __syncthreads();
        tile[t] += x;
        __syncthreads();
    }
    if (i < NT) tmp[i] = tile[t] - v;
    if (t == 255) bsum[blockIdx.x] = tile[255];
}

__global__ void scan2_kernel(const int* __restrict__ bsum, int* __restrict__ boff,
                             int* __restrict__ row_start) {
    __shared__ int tile[256];
    int t = threadIdx.x;
    int v = (t < SCAN_NB) ? bsum[t] : 0;
    tile[t] = v;
    __syncthreads();
    for (int off = 1; off < 256; off <<= 1) {
        int x = (t >= off) ? tile[t - off] : 0;
        __syncthreads();
        tile[t] += x;
        __syncthreads();
    }
    if (t < SCAN_NB) boff[t] = tile[t] - v;
    if (t == 255) row_start[NT] = tile[255];
}

__global__ void scan3_kernel(const int* __restrict__ tmp, const int* __restrict__ boff,
                             int* __restrict__ row_start, int* __restrict__ cursor) {
    int i = blockIdx.x * 256 + threadIdx.x;
    if (i < NT) {
        int rs = tmp[i] + boff[blockIdx.x];
        row_start[i] = rs;
        cursor[i] = rs;
    }
}

__global__ void fill_kernel(const int* __restrict__ ei1, const int* __restrict__ ei2,
                            int* __restrict__ cursor, int* __restrict__ csr_src) {
    int e = blockIdx.x * blockDim.x + threadIdx.x;
    if (e >= ET) return;
    int s, d;
    if (e < E1) { s = ei1[e]; d = ei1[E1 + e]; }
    else        { int e2 = e - E1; s = ei2[e2] + N1; d = ei2[E1 + e2] + N1; }
    int p = atomicAdd(&cursor[d], 1);
    csr_src[p] = s;
}

// ---------------- conversions ----------------
__global__ void convx_kernel(const float* __restrict__ x, unsigned short* __restrict__ xb, int n4) {
    int i = blockIdx.x * 256 + threadIdx.x;
    if (i < n4) {
        float4 f = ((const float4*)x)[i];
        ushort4 u;
        u.x = f2bf(f.x); u.y = f2bf(f.y); u.z = f2bf(f.z); u.w = f2bf(f.w);
        ((ushort4*)xb)[i] = u;
    }
}

// W[K][N] fp32 -> Wt[N][K] bf16 (tiled transpose)
__global__ void convw_kernel(const float* __restrict__ W, unsigned short* __restrict__ Wt,
                             int K, int N) {
    __shared__ float tile[32][33];
    int k0 = blockIdx.x * 32, n0 = blockIdx.y * 32;
    int tx = threadIdx.x & 31, ty = threadIdx.x >> 5;
    for (int r = ty; r < 32; r += 8) tile[r][tx] = W[(size_t)(k0 + r) * N + n0 + tx];
    __syncthreads();
    for (int r = ty; r < 32; r += 8)
        Wt[(size_t)(n0 + r) * K + k0 + tx] = f2bf(tile[tx][r]);
}

// ---------------- GIN aggregation, XCD-slab + deep-pipeline version -----------
// Slab of 32 cols pinned per XCD (blockIdx%8) => per-XCD WS = 2.56 MB < 4 MB L2.
// Unroll-8 batches: 8 independent named gather regs so the compiler issues all
// 8 global_load_dwordx4 before the first accumulate waitcnt (deep MLP).
#define ACC8(u) do { \
    acc[0] += bflo((u).x); acc[1] += bfhi((u).x); \
    acc[2] += bflo((u).y); acc[3] += bfhi((u).y); \
    acc[4] += bflo((u).z); acc[5] += bfhi((u).z); \
    acc[6] += bflo((u).w); acc[7] += bfhi((u).w); } while (0)

template<int LPR, int NSLAB>   // LPR = uint4 per full row (D/8); NSLAB = LPR/4
__launch_bounds__(256, 8)
__global__ void agg_slab_kernel(const unsigned short* __restrict__ x,
                                const int* __restrict__ row_start,
                                const int* __restrict__ csr_src,
                                unsigned short* __restrict__ h) {
    const int GRPS = NT / 64;                  // 625 node-groups of 64
    int b = blockIdx.x;
    int phase = b / (8 * GRPS);                // 0..NSLAB/8-1
    int rem = b % (8 * GRPS);
    int slab = phase * 8 + (rem & 7);          // stays on XCD (rem&7)
    int grp = rem >> 3;
    int nid = grp * 64 + (threadIdx.x >> 2);
    int c = threadIdx.x & 3;
    int chunk = slab * 4 + c;                  // uint4 index within row
    const uint4* Xc = (const uint4*)x + chunk;
    uint4 v = Xc[(size_t)nid * LPR];
    float acc[8];
    acc[0] = bflo(v.x); acc[1] = bfhi(v.x);
    acc[2] = bflo(v.y); acc[3] = bfhi(v.y);
    acc[4] = bflo(v.z); acc[5] = bfhi(v.z);
    acc[6] = bflo(v.w); acc[7] = bfhi(v.w);
    int s = row_start[nid], e = row_start[nid + 1];
    int p = s;
    // 8-deep batches: all loads independent -> 8 in flight before accumulation
    for (; p + 8 <= e; p += 8) {
        int n0 = csr_src[p + 0], n1 = csr_src[p + 1], n2 = csr_src[p + 2], n3 = csr_src[p + 3];
        int n4 = csr_src[p + 4], n5 = csr_src[p + 5], n6 = csr_src[p + 6], n7 = csr_src[p + 7];
        uint4 u0 = Xc[(size_t)n0 * LPR];
        uint4 u1 = Xc[(size_t)n1 * LPR];
        uint4 u2 = Xc[(size_t)n2 * LPR];
        uint4 u3 = Xc[(size_t)n3 * LPR];
        uint4 u4 = Xc[(size_t)n4 * LPR];
        uint4 u5 = Xc[(size_t)n5 * LPR];
        uint4 u6 = Xc[(size_t)n6 * LPR];
        uint4 u7 = Xc[(size_t)n7 * LPR];
        ACC8(u0); ACC8(u1); ACC8(u2); ACC8(u3);
        ACC8(u4); ACC8(u5); ACC8(u6); ACC8(u7);
    }
    for (; p + 2 <= e; p += 2) {
        int n0 = csr_src[p + 0], n1 = csr_src[p + 1];
        uint4 u0 = Xc[(size_t)n0 * LPR];
        uint4 u1 = Xc[(size_t)n1 * LPR];
        ACC8(u0); ACC8(u1);
    }
    if (p < e) {
        int n0 = csr_src[p];
        uint4 u0 = Xc[(size_t)n0 * LPR];
        ACC8(u0);
    }
    uint4 o;
    o.x = (unsigned)f2bf(acc[0]) | ((unsigned)f2bf(acc[1]) << 16);
    o.y = (unsigned)f2bf(acc[2]) | ((unsigned)f2bf(acc[3]) << 16);
    o.z = (unsigned)f2bf(acc[4]) | ((unsigned)f2bf(acc[5]) << 16);
    o.w = (unsigned)f2bf(acc[6]) | ((unsigned)f2bf(acc[7]) << 16);
    ((uint4*)h)[(size_t)nid * LPR + chunk] = o;
}

// ---------------- bf16 MFMA GEMM: C = relu(A[MP,K] @ W[K,N] + bias), bf16 out ----
__launch_bounds__(256)
__global__ void gemm_mfma(const unsigned short* __restrict__ A,
                          const unsigned short* __restrict__ Wt,
                          const float* __restrict__ bias,
                          unsigned short* __restrict__ C,
                          int K, int N) {
    __shared__ unsigned short As[128 * 32];
    __shared__ unsigned short Bs[128 * 32];
    int tid = threadIdx.x;
    int lane = tid & 63;
    int w = tid >> 6;
    int wr = w >> 1, wc = w & 1;
    int row0 = blockIdx.x * 128;
    int col0 = blockIdx.y * 128;
    floatx4 acc[4][4] = {};
    int lr = tid >> 2;
    int c8 = (tid & 3) * 8;
    const unsigned short* Ag = A + (size_t)row0 * K;
    const unsigned short* Bg = Wt + (size_t)col0 * K;

    for (int kt = 0; kt < K; kt += 32) {
#pragma unroll
        for (int l = 0; l < 2; ++l) {
            int r = l * 64 + lr;
            __builtin_amdgcn_global_load_lds(
                (const __attribute__((address_space(1))) void*)(Ag + (size_t)r * K + kt + c8),
                (__attribute__((address_space(3))) void*)(As + l * 2048 + tid * 8),
                16, 0, 0);
            __builtin_amdgcn_global_load_lds(
                (const __attribute__((address_space(1))) void*)(Bg + (size_t)r * K + kt + c8),
                (__attribute__((address_space(3))) void*)(Bs + l * 2048 + tid * 8),
                16, 0, 0);
        }
        __syncthreads();
        short8 af[4], bf[4];
        int q8 = (lane >> 4) * 8;
#pragma unroll
        for (int i = 0; i < 4; ++i) {
            int m = wr * 64 + i * 16 + (lane & 15);
            af[i] = *(const short8*)&As[m * 32 + q8];
            int n = wc * 64 + i * 16 + (lane & 15);
            bf[i] = *(const short8*)&Bs[n * 32 + q8];
        }
#pragma unroll
        for (int i = 0; i < 4; ++i)
#pragma unroll
            for (int j = 0; j < 4; ++j)
                acc[i][j] = __builtin_amdgcn_mfma_f32_16x16x32_bf16(af[i], bf[j], acc[i][j], 0, 0, 0);
        __syncthreads();
    }
    int q = lane >> 4;
    int cn = lane & 15;
#pragma unroll
    for (int j = 0; j < 4; ++j) {
        int col = col0 + wc * 64 + j * 16 + cn;
        float bv = bias[col];
#pragma unroll
        for (int i = 0; i < 4; ++i) {
            int rowb = row0 + wr * 64 + i * 16 + q * 4;
#pragma unroll
            for (int r = 0; r < 4; ++r) {
                float vv = fmaxf(acc[i][j][r] + bv, 0.f);
                C[(size_t)(rowb + r) * N + col] = f2bf(vv);
            }
        }
    }
}

// ---------------- final linear [NT,512]bf16 @ [512,2]fp32 + b ----------------
__global__ void lin_kernel(const unsigned short* __restrict__ A, const float* __restrict__ w,
                           const float* __restrict__ b, float* __restrict__ o, int M) {
    int wave = threadIdx.x >> 6;
    int lane = threadIdx.x & 63;
    int row = blockIdx.x * 4 + wave;
    if (row >= M) return;
    const uint4* Ar = (const uint4*)(A + (size_t)row * 512);
    uint4 u = Ar[lane];
    float f[8];
    f[0] = bflo(u.x); f[1] = bfhi(u.x); f[2] = bflo(u.y); f[3] = bfhi(u.y);
    f[4] = bflo(u.z); f[5] = bfhi(u.z); f[6] = bflo(u.w); f[7] = bfhi(u.w);
    float s0 = 0.f, s1 = 0.f;
#pragma unroll
    for (int j = 0; j < 8; ++j) {
        int base = (lane * 8 + j) * 2;
        s0 = fmaf(f[j], w[base + 0], s0);
        s1 = fmaf(f[j], w[base + 1], s1);
    }
#pragma unroll
    for (int off = 32; off > 0; off >>= 1) {
        s0 += __shfl_down(s0, off, 64);
        s1 += __shfl_down(s1, off, 64);
    }
    if (lane == 0) { o[row * 2] = s0 + b[0]; o[row * 2 + 1] = s1 + b[1]; }
}

// ---------------- pairwise distance ----------------
__global__ void dist_kernel(const float* __restrict__ o, float* __restrict__ dist) {
    int i = blockIdx.x * blockDim.x + threadIdx.x;
    if (i < N1) {
        float2 a = ((const float2*)o)[i];
        float2 b = ((const float2*)o)[N1 + i];
        float d0 = a.x - b.x + 1e-6f, d1 = a.y - b.y + 1e-6f;
        dist[i] = sqrtf(d0 * d0 + d1 * d1);
    }
}

// ---------------- radix-select top-k ----------------
__global__ void histd_kernel(const float* __restrict__ dist, int* __restrict__ hist) {
    int i = blockIdx.x * blockDim.x + threadIdx.x;
    if (i < N1) {
        unsigned u = __float_as_uint(dist[i]);
        atomicAdd(&hist[u >> 19], 1);
    }
}

__global__ void selk_kernel(const int* __restrict__ hist, int* __restrict__ selout) {
    __shared__ int tile[256];
    int t = threadIdx.x;
    int running = 0;
    for (int tb = 0; tb < 16; ++tb) {
        int idx = 4095 - (tb * 256 + t);
        int v = hist[idx];
        tile[t] = v;
        __syncthreads();
        for (int off = 1; off < 256; off <<= 1) {
            int x = (t >= off) ? tile[t - off] : 0;
            __syncthreads();
            tile[t] += x;
            __syncthreads();
        }
        int incl = running + tile[t];
        if (incl >= TOPK && incl - v < TOPK) selout[0] = idx;
        running += tile[255];
        __syncthreads();
        if (running >= TOPK) break;
    }
}

__global__ void compact_kernel(const float* __restrict__ dist, const int* __restrict__ selout,
                               int* __restrict__ nc, float* __restrict__ cd, int* __restrict__ ci) {
    int i = blockIdx.x * blockDim.x + threadIdx.x;
    if (i >= N1) return;
    float d = dist[i];
    int b = (int)(__float_as_uint(d) >> 19);
    if (b >= selout[0]) {
        int p = atomicAdd(nc, 1);
        cd[p] = d;
        ci[p] = i;
    }
}

#define CCH 2048
__global__ void rankc_kernel(const float* __restrict__ cd, const int* __restrict__ ci,
                             const int* __restrict__ nc_p, float* __restrict__ vals) {
    __shared__ float ds[CCH];
    __shared__ int   di_[CCH];
    int nc = *nc_p;
    int t = threadIdx.x;
    int q = blockIdx.x * 256 + t;
    float dq = 0.f; int iq = 0;
    if (q < nc) { dq = cd[q]; iq = ci[q]; }
    int cnt = 0;
    for (int c0 = 0; c0 < nc; c0 += CCH) {
        int lim = min(CCH, nc - c0);
        for (int j = t; j < lim; j += 256) { ds[j] = cd[c0 + j]; di_[j] = ci[c0 + j]; }
        __syncthreads();
        if (q < nc) {
            for (int j = 0; j < lim; ++j) {
                float dj = ds[j];
                cnt += (dj > dq) || (dj == dq && di_[j] < iq);
            }
        }
        __syncthreads();
    }
    if (q < nc && cnt < TOPK) vals[cnt] = dq;
}

// ---------------- head MLP ----------------
__launch_bounds__(512)
__global__ void head_kernel(const float* __restrict__ vals,
                            const float* __restrict__ fc1_w, const float* __restrict__ fc1_b,
                            const float* __restrict__ ln1_g, const float* __restrict__ ln1_b,
                            const float* __restrict__ fc2_w, const float* __restrict__ fc2_b,
                            const float* __restrict__ ln2_g, const float* __restrict__ ln2_b,
                            const float* __restrict__ fc3_w, const float* __restrict__ fc3_b,
                            float* __restrict__ out) {
    __shared__ float sv[TOPK];
    __shared__ float a1[128];
    __shared__ float red[512];
    __shared__ float s_m, s_r;
    int t = threadIdx.x;
    for (int i = t; i < TOPK; i += 512) sv[i] = vals[i];
    __syncthreads();
    float h1 = 0.f;
    if (t < 128) {
        h1 = fc1_b[t];
        for (int j = 0; j < TOPK; ++j) h1 = fmaf(sv[j], fc1_w[j * 128 + t], h1);
    }
    red[t] = (t < 128) ? h1 : 0.f; __syncthreads();
    for (int s = 256; s > 0; s >>= 1) { if (t < s) red[t] += red[t + s]; __syncthreads(); }
    if (t == 0) s_m = red[0] / 128.f;
    __syncthreads();
    float m1 = s_m;
    float dv = (t < 128) ? (h1 - m1) : 0.f;
    red[t] = dv * dv; __syncthreads();
    for (int s = 256; s > 0; s >>= 1) { if (t < s) red[t] += red[t + s]; __syncthreads(); }
    if (t == 0) s_r = rsqrtf(red[0] / 128.f + 1e-5f);
    __syncthreads();
    float r1 = s_r;
    if (t < 128) a1[t] = fmaxf((h1 - m1) * r1 * ln1_g[t] + ln1_b[t], 0.f);
    __syncthreads();
    float h2 = fc2_b[t];
    for (int j = 0; j < 128; ++j) h2 = fmaf(a1[j], fc2_w[j * 512 + t], h2);
    red[t] = h2; __syncthreads();
    for (int s = 256; s > 0; s >>= 1) { if (t < s) red[t] += red[t + s]; __syncthreads(); }
    if (t == 0) s_m = red[0] / 512.f;
    __syncthreads();
    float m2 = s_m;
    float d2 = h2 - m2;
    red[t] = d2 * d2; __syncthreads();
    for (int s = 256; s > 0; s >>= 1) { if (t < s) red[t] += red[t + s]; __syncthreads(); }
    if (t == 0) s_r = rsqrtf(red[0] / 512.f + 1e-5f);
    __syncthreads();
    float r2 = s_r;
    float y2 = fmaxf((h2 - m2) * r2 * ln2_g[t] + ln2_b[t], 0.f);
    red[t] = y2 * fc3_w[t]; __syncthreads();
    for (int s = 256; s > 0; s >>= 1) { if (t < s) red[t] += red[t + s]; __syncthreads(); }
    if (t == 0) out[0] = 1.f / (1.f + expf(-(red[0] + fc3_b[0])));
}

extern "C" void kernel_launch(void* const* d_in, const int* in_sizes, int n_in,
                              void* d_out, int out_size, void* d_ws, size_t ws_size,
                              hipStream_t stream) {
    const float* x1   = (const float*)d_in[0];
    const int*   ei1  = (const int*)d_in[1];
    const float* x2   = (const float*)d_in[2];
    const int*   ei2  = (const int*)d_in[3];
    const float* w11  = (const float*)d_in[4];
    const float* b11  = (const float*)d_in[5];
    const float* w12  = (const float*)d_in[6];
    const float* b12  = (const float*)d_in[7];
    const float* w21  = (const float*)d_in[8];
    const float* b21  = (const float*)d_in[9];
    const float* w22  = (const float*)d_in[10];
    const float* b22  = (const float*)d_in[11];
    const float* w31  = (const float*)d_in[12];
    const float* b31  = (const float*)d_in[13];
    const float* w32  = (const float*)d_in[14];
    const float* b32  = (const float*)d_in[15];
    const float* lw   = (const float*)d_in[16];
    const float* lb   = (const float*)d_in[17];
    const float* fc1w = (const float*)d_in[18];
    const float* fc1b = (const float*)d_in[19];
    const float* ln1g = (const float*)d_in[20];
    const float* ln1b = (const float*)d_in[21];
    const float* fc2w = (const float*)d_in[22];
    const float* fc2b = (const float*)d_in[23];
    const float* ln2g = (const float*)d_in[24];
    const float* ln2b = (const float*)d_in[25];
    const float* fc3w = (const float*)d_in[26];
    const float* fc3b = (const float*)d_in[27];

    char* ws = (char*)d_ws;
    size_t off = 0;
    auto alloc = [&](size_t bytes) -> void* {
        void* p = ws + off;
        off += (bytes + 255) & ~(size_t)255;
        return p;
    };
    unsigned short* H0  = (unsigned short*)alloc((size_t)MP * HID_D * 2);
    unsigned short* H1  = (unsigned short*)alloc((size_t)MP * HID_D * 2);
    unsigned short* XB  = H1;   // alias: XB dead before gemm1 writes H1
    unsigned short* wt11 = (unsigned short*)alloc((size_t)HID_D * FIN_D * 2);
    unsigned short* wt12 = (unsigned short*)alloc((size_t)HID_D * HID_D * 2);
    unsigned short* wt21 = (unsigned short*)alloc((size_t)HID_D * HID_D * 2);
    unsigned short* wt22 = (unsigned short*)alloc((size_t)HID_D * HID_D * 2);
    unsigned short* wt31 = (unsigned short*)alloc((size_t)HID_D * HID_D * 2);
    unsigned short* wt32 = (unsigned short*)alloc((size_t)HID_D * HID_D * 2);
    float* o         = (float*)alloc((size_t)NT * 2 * 4);
    float* dist      = (float*)alloc((size_t)N1 * 4);
    float* vals      = (float*)alloc((size_t)TOPK * 4);
    int*   row_start = (int*)alloc((size_t)(NT + 1) * 4);
    int*   cursor    = (int*)alloc((size_t)NT * 4);
    int*   deg       = (int*)alloc((size_t)NT * 4);
    int*   scan_tmp  = (int*)alloc((size_t)NT * 4);
    int*   bsum      = (int*)alloc((size_t)SCAN_NB * 4);
    int*   boff      = (int*)alloc((size_t)SCAN_NB * 4);
    int*   csr_src   = (int*)alloc((size_t)ET * 4);
    int*   selblk    = (int*)alloc((size_t)(4096 + 64) * 4);  // hist + nc
    int*   hist      = selblk;
    int*   nc        = selblk + 4096;
    int*   selout    = (int*)alloc(2 * 4);
    float* cd        = (float*)alloc((size_t)N1 * 4);
    int*   ci        = (int*)alloc((size_t)N1 * 4);

    // ---- weight / input conversions ----
    {
        dim3 g11(FIN_D / 32, HID_D / 32);
        dim3 g55(HID_D / 32, HID_D / 32);
        convw_kernel<<<g11, 256, 0, stream>>>(w11, wt11, FIN_D, HID_D);
        convw_kernel<<<g55, 256, 0, stream>>>(w12, wt12, HID_D, HID_D);
        convw_kernel<<<g55, 256, 0, stream>>>(w21, wt21, HID_D, HID_D);
        convw_kernel<<<g55, 256, 0, stream>>>(w22, wt22, HID_D, HID_D);
        convw_kernel<<<g55, 256, 0, stream>>>(w31, wt31, HID_D, HID_D);
        convw_kernel<<<g55, 256, 0, stream>>>(w32, wt32, HID_D, HID_D);
        int n4 = N1 * FIN_D / 4;
        convx_kernel<<<(n4 + 255) / 256, 256, 0, stream>>>(x1, XB, n4);
        convx_kernel<<<(n4 + 255) / 256, 256, 0, stream>>>(x2, XB + (size_t)N1 * FIN_D, n4);
    }

    // ---- CSR build (both graphs, global node ids) ----
    hipMemsetAsync(deg, 0, NT * sizeof(int), stream);
    hist_kernel<<<(ET + 255) / 256, 256, 0, stream>>>(ei1, ei2, deg);
    scan1_kernel<<<SCAN_NB, 256, 0, stream>>>(deg, scan_tmp, bsum);
    scan2_kernel<<<1, 256, 0, stream>>>(bsum, boff, row_start);
    scan3_kernel<<<SCAN_NB, 256, 0, stream>>>(scan_tmp, boff, row_start, cursor);
    fill_kernel<<<(ET + 255) / 256, 256, 0, stream>>>(ei1, ei2, cursor, csr_src);

    // ---- GNN pipeline (both graphs batched) ----
    dim3 gemm_grid(MP / 128, HID_D / 128);
    const int GRPS = NT / 64;   // 625
    // layer 1 (D=256 input): 8 slabs
    agg_slab_kernel<32, 8><<<8 * GRPS, 256, 0, stream>>>(XB, row_start, csr_src, H0);
    gemm_mfma<<<gemm_grid, 256, 0, stream>>>(H0, wt11, b11, H1, FIN_D, HID_D);   // overwrites XB (dead)
    gemm_mfma<<<gemm_grid, 256, 0, stream>>>(H1, wt12, b12, H0, HID_D, HID_D);
    // layer 2 (D=512): 16 slabs, 2 phases
    agg_slab_kernel<64, 16><<<16 * GRPS, 256, 0, stream>>>(H0, row_start, csr_src, H1);
    gemm_mfma<<<gemm_grid, 256, 0, stream>>>(H1, wt21, b21, H0, HID_D, HID_D);
    gemm_mfma<<<gemm_grid, 256, 0, stream>>>(H0, wt22, b22, H1, HID_D, HID_D);
    // layer 3
    agg_slab_kernel<64, 16><<<16 * GRPS, 256, 0, stream>>>(H1, row_start, csr_src, H0);
    gemm_mfma<<<gemm_grid, 256, 0, stream>>>(H0, wt31, b31, H1, HID_D, HID_D);
    gemm_mfma<<<gemm_grid, 256, 0, stream>>>(H1, wt32, b32, H0, HID_D, HID_D);
    // final linear [NT,512] -> [NT,2]
    lin_kernel<<<(NT + 3) / 4, 256, 0, stream>>>(H0, lw, lb, o, NT);

    // ---- distance + radix-select top-k ----
    dist_kernel<<<(N1 + 255) / 256, 256, 0, stream>>>(o, dist);
    hipMemsetAsync(selblk, 0, (4096 + 64) * sizeof(int), stream);
    histd_kernel<<<(N1 + 255) / 256, 256, 0, stream>>>(dist, hist);
    selk_kernel<<<1, 256, 0, stream>>>(hist, selout);
    compact_kernel<<<(N1 + 255) / 256, 256, 0, stream>>>(dist, selout, nc, cd, ci);
    rankc_kernel<<<(N1 + 255) / 256, 256, 0, stream>>>(cd, ci, nc, vals);

    // ---- head MLP ----
    head_kernel<<<1, 512, 0, stream>>>(vals, fc1w, fc1b, ln1g, ln1b,
                                       fc2w, fc2b, ln2g, ln2b, fc3w, fc3b,
                                       (float*)d_out);
}